// Round 2
// baseline (1232.467 us; speedup 1.0000x reference)
//
#include <hip/hip_runtime.h>
#include <cstdint>
#include <cstddef>

typedef unsigned short u16t;
typedef __attribute__((ext_vector_type(8))) short short8;   // 8 x bf16 (4 VGPRs)
typedef __attribute__((ext_vector_type(4))) float float4v;  // MFMA C/D frag

#define NATOMS 50400
#define SSP    7
#define DIN    1008
#define KP     1024     // layer-1 K padded to 32*32
#define GRP    7200     // atoms per species
#define GPAD   7296     // 57 * 128
#define NTILE  57
#define H0D    256
#define H1D    192
#define H2D    160

// ---- workspace byte offsets (all 16B aligned) ----
#define OFF_CNT   0ull
#define OFF_SRC   256ull                 // 7*7296*4 = 204288
#define OFF_X     204544ull              // 7*7296*1024*2 = 104595456
#define OFF_W0T   104800000ull           // 56*256*1024*2 = 29360128
#define OFF_W1T   134160128ull           // 56*192*256*2  = 5505024
#define OFF_W2T   139665152ull           // 56*160*192*2  = 3440640

__device__ __forceinline__ u16t f2bf(float f) {
    union { float f; unsigned u; } x; x.f = f;
    unsigned r = x.u + 0x7fffu + ((x.u >> 16) & 1u);   // RNE
    return (u16t)(r >> 16);
}
__device__ __forceinline__ float bf2f(u16t h) {
    return __uint_as_float(((unsigned)h) << 16);
}
__device__ __forceinline__ float celu_f(float x) {
    return x > 0.f ? x : 0.1f * (__expf(x * 10.f) - 1.f);
}
// async global->LDS, 16B per lane; LDS dest = wave-uniform base + lane*16
__device__ __forceinline__ void gll16(const void* g, void* l) {
    __builtin_amdgcn_global_load_lds(
        (const __attribute__((address_space(1))) void*)g,
        (__attribute__((address_space(3))) void*)l, 16, 0, 0);
}

// ---------------- prep kernels ----------------

// atom -> slot within its species block; wave-aggregated atomics
// (7 ballots + <=7 atomics per wave instead of 64 contended atomics)
__global__ void assign_k(const int* __restrict__ sp, int* __restrict__ cnt,
                         int* __restrict__ src_of) {
    int i = blockIdx.x * 256 + threadIdx.x;
    int lane = threadIdx.x & 63;
    int s = (i < NATOMS) ? sp[i] : -1;
#pragma unroll
    for (int t = 0; t < SSP; ++t) {
        unsigned long long m = __ballot(s == t);
        if (s == t) {
            int leader = __ffsll((unsigned long long)m) - 1;
            int rank = __popcll(m & ((1ull << lane) - 1ull));
            int base = 0;
            if (lane == leader) base = atomicAdd(&cnt[t], __popcll(m));
            base = __shfl(base, leader);
            src_of[t * GPAD + base + rank] = i;
        }
    }
}

// gather aev rows into species-sorted bf16 X [7][7296][1024]; pad rows/cols = 0
__global__ void gather_k(const float* __restrict__ aev, const int* __restrict__ src_of,
                         u16t* __restrict__ X) {
    int b = blockIdx.x;            // s*GPAD + row
    int row = b % GPAD;
    int t = threadIdx.x;
    int c = t * 4;
    ushort4 o; o.x = 0; o.y = 0; o.z = 0; o.w = 0;
    if (row < GRP && c < DIN) {
        int i = src_of[b];
        float4 v = *(const float4*)(aev + (size_t)i * DIN + c);
        o.x = f2bf(v.x); o.y = f2bf(v.y); o.z = f2bf(v.z); o.w = f2bf(v.w);
    }
    *(ushort4*)(X + (size_t)b * KP + c) = o;
}

// src [batch][K_in][C] fp32 -> dst [batch][C][K_out] bf16, zero-fill K_in..K_out
__global__ void transpose_convert_k(const float* __restrict__ src, u16t* __restrict__ dst,
                                    int K_in, int C, int K_out) {
    __shared__ float tile[64][65];
    int b = blockIdx.z;
    int k0 = blockIdx.x * 64, c0 = blockIdx.y * 64;
    int tx = threadIdx.x & 63, ty = threadIdx.x >> 6;   // ty 0..3
    const float* sp = src + (size_t)b * K_in * C;
#pragma unroll
    for (int i = 0; i < 16; ++i) {
        int kl = i * 4 + ty;
        int k = k0 + kl, c = c0 + tx;
        float v = (k < K_in && c < C) ? sp[(size_t)k * C + c] : 0.f;
        tile[kl][tx] = v;
    }
    __syncthreads();
    u16t* dp = dst + (size_t)b * C * K_out;
#pragma unroll
    for (int i = 0; i < 16; ++i) {
        int cl = i * 4 + ty;
        int c = c0 + cl, k = k0 + tx;
        if (c < C && k < K_out)
            dp[(size_t)c * K_out + k] = f2bf(tile[tx][cl]);
    }
}

// ---------------- fused per-(species,model,row-tile) MLP ----------------
// grid (57, 56), 512 threads (8 waves)
__launch_bounds__(512, 2)
__global__ void fused_mlp(const u16t* __restrict__ X, const u16t* __restrict__ W0T,
                          const u16t* __restrict__ W1T, const u16t* __restrict__ W2T,
                          const float* __restrict__ W3,
                          const float* __restrict__ b0, const float* __restrict__ b1,
                          const float* __restrict__ b2, const float* __restrict__ b3,
                          float* __restrict__ out) {
    // A-stage double buffer 2x8KB; activations H0 64KB, H1 48KB. Total 128KB.
    __shared__ __attribute__((aligned(16))) char lds_stage[16384];
    __shared__ __attribute__((aligned(16))) char lds_act0[65536];
    __shared__ __attribute__((aligned(16))) char lds_act1[49152];

    const int tid  = threadIdx.x;
    const int w    = tid >> 6;
    const int lane = tid & 63;
    const int l15  = lane & 15;
    const int quad = lane >> 4;          // 0..3
    const int tile = blockIdx.x;         // 0..56
    const int bsm  = blockIdx.y;         // s*8+m
    const int s    = bsm >> 3;

    const u16t* Xp  = X + ((size_t)s * GPAD + (size_t)tile * 128) * KP;
    const u16t* W0p = W0T + (size_t)bsm * H0D * KP;

    // A-staging lane mapping (source-side XOR swizzle so frag reads are 2-way free):
    // LDS chunk u = w*64+lane holds global (row r=u>>2, part p=(u&3)^((r>>1)&3))
    const int stg_u = (w << 6) | lane;
    const int stg_r = stg_u >> 2;
    const int stg_p = (stg_u & 3) ^ ((stg_r >> 1) & 3);
    const u16t* stg_g = Xp + (size_t)stg_r * KP + stg_p * 8;   // + k0 per iter
    char* const stg_l0 = lds_stage + (w << 10);

    // ======== Phase 1: H0 = celu(X[128x1024] @ W0[1024x256] + b0) ========
    float4v acc[4][4];
#pragma unroll
    for (int i = 0; i < 4; ++i)
#pragma unroll
        for (int j = 0; j < 4; ++j) acc[i][j] = (float4v){0.f, 0.f, 0.f, 0.f};

    const int RW = (w & 1) * 64;
    const int CW = (w >> 1) * 64;

    // precomputed A-frag byte offsets (within an 8KB buffer)
    int aoff[4];
#pragma unroll
    for (int rt = 0; rt < 4; ++rt) {
        int r = RW + rt * 16 + l15;
        aoff[rt] = (r * 4 + ((quad ^ (r >> 1)) & 3)) * 16;
    }
    // B fragment source pointers (global, fragment-shaped), + k0 per iter
    const u16t* bptr[4];
#pragma unroll
    for (int ct = 0; ct < 4; ++ct) {
        int c = CW + ct * 16 + l15;
        bptr[ct] = W0p + (size_t)c * KP + quad * 8;
    }

    // preload: A(0) -> buf0, B(0) -> regs
    gll16(stg_g, stg_l0);
    short8 bc[4];
#pragma unroll
    for (int ct = 0; ct < 4; ++ct) bc[ct] = *(const short8*)(bptr[ct]);
    __syncthreads();

    for (int kc = 0; kc < 32; ++kc) {
        const int k0 = kc * 32;
        if (kc + 1 < 32)   // stage next A-tile into the other buffer (async)
            gll16(stg_g + k0 + 32, stg_l0 + (((kc + 1) & 1) << 13));
        const char* abuf = lds_stage + ((kc & 1) << 13);
        short8 af[4];
#pragma unroll
        for (int rt = 0; rt < 4; ++rt)
            af[rt] = *(const short8*)(abuf + aoff[rt]);
        short8 bn[4];
        const int k0n = (kc + 1 < 32) ? k0 + 32 : k0;
#pragma unroll
        for (int ct = 0; ct < 4; ++ct)
            bn[ct] = *(const short8*)(bptr[ct] + k0n);
#pragma unroll
        for (int rt = 0; rt < 4; ++rt)
#pragma unroll
            for (int ct = 0; ct < 4; ++ct)
                acc[rt][ct] = __builtin_amdgcn_mfma_f32_16x16x32_bf16(af[rt], bc[ct], acc[rt][ct], 0, 0, 0);
#pragma unroll
        for (int ct = 0; ct < 4; ++ct) bc[ct] = bn[ct];
        __syncthreads();
    }
    { // epilogue 1 -> lds_act0 [128][256] bf16, 16B-chunk XOR swizzle (mask 31)
        float bias[4];
#pragma unroll
        for (int ct = 0; ct < 4; ++ct) bias[ct] = b0[bsm * H0D + CW + ct * 16 + l15];
#pragma unroll
        for (int rt = 0; rt < 4; ++rt)
#pragma unroll
            for (int ct = 0; ct < 4; ++ct) {
                int col = CW + ct * 16 + l15;
                int q = col >> 3;
#pragma unroll
                for (int rg = 0; rg < 4; ++rg) {
                    int row = RW + rt * 16 + quad * 4 + rg;
                    float v = celu_f(acc[rt][ct][rg] + bias[ct]);
                    int addr = row * 512 + (((q ^ row) & 31) * 8 + (col & 7)) * 2;
                    *(u16t*)(lds_act0 + addr) = f2bf(v);
                }
            }
    }
    __syncthreads();

    // ======== Phase 2: H1 = celu(H0[128x256] @ W1[256x192] + b1) ========
    // A from LDS act0, B prefetched from global; no barriers in loop.
    float4v acc2[4][3];
#pragma unroll
    for (int i = 0; i < 4; ++i)
#pragma unroll
        for (int j = 0; j < 3; ++j) acc2[i][j] = (float4v){0.f, 0.f, 0.f, 0.f};
    const int RW2 = (w & 1) * 64;
    const int CW2 = (w >> 1) * 48;
    const u16t* W1p = W1T + (size_t)bsm * H1D * H0D;   // [192][256]
    const u16t* b2ptr[3];
#pragma unroll
    for (int ct = 0; ct < 3; ++ct) {
        int c = CW2 + ct * 16 + l15;
        b2ptr[ct] = W1p + (size_t)c * H0D + quad * 8;
    }
    short8 bc2[3];
#pragma unroll
    for (int ct = 0; ct < 3; ++ct) bc2[ct] = *(const short8*)(b2ptr[ct]);

    for (int kc = 0; kc < 8; ++kc) {
        const int k0n = (kc + 1 < 8) ? (kc + 1) * 32 : kc * 32;
        short8 af[4];
#pragma unroll
        for (int rt = 0; rt < 4; ++rt) {
            int r = RW2 + rt * 16 + l15;
            int q = kc * 4 + quad;
            af[rt] = *(const short8*)(lds_act0 + r * 512 + ((q ^ r) & 31) * 16);
        }
        short8 bn2[3];
#pragma unroll
        for (int ct = 0; ct < 3; ++ct)
            bn2[ct] = *(const short8*)(b2ptr[ct] + k0n);
#pragma unroll
        for (int rt = 0; rt < 4; ++rt)
#pragma unroll
            for (int ct = 0; ct < 3; ++ct)
                acc2[rt][ct] = __builtin_amdgcn_mfma_f32_16x16x32_bf16(af[rt], bc2[ct], acc2[rt][ct], 0, 0, 0);
#pragma unroll
        for (int ct = 0; ct < 3; ++ct) bc2[ct] = bn2[ct];
    }
    { // epilogue 2 -> lds_act1 [128][192] bf16, chunk swizzle (low 3 bits)
        float bias[3];
#pragma unroll
        for (int ct = 0; ct < 3; ++ct) bias[ct] = b1[bsm * H1D + CW2 + ct * 16 + l15];
#pragma unroll
        for (int rt = 0; rt < 4; ++rt)
#pragma unroll
            for (int ct = 0; ct < 3; ++ct) {
                int col = CW2 + ct * 16 + l15;
                int q = col >> 3;
#pragma unroll
                for (int rg = 0; rg < 4; ++rg) {
                    int row = RW2 + rt * 16 + quad * 4 + rg;
                    float v = celu_f(acc2[rt][ct][rg] + bias[ct]);
                    int qs = (q & ~7) | ((q ^ row) & 7);
                    int addr = row * 384 + (qs * 8 + (col & 7)) * 2;
                    *(u16t*)(lds_act1 + addr) = f2bf(v);
                }
            }
    }
    __syncthreads();

    // ======== Phase 3: H2 = celu(H1[128x192] @ W2[192x160] + b2) ========
    float4v acc3[2][5];
#pragma unroll
    for (int i = 0; i < 2; ++i)
#pragma unroll
        for (int j = 0; j < 5; ++j) acc3[i][j] = (float4v){0.f, 0.f, 0.f, 0.f};
    const int RW3 = (w & 3) * 32;
    const int CW3 = (w >> 2) * 80;
    const u16t* W2p = W2T + (size_t)bsm * H2D * H1D;   // [160][192]
    const u16t* b3ptr[5];
#pragma unroll
    for (int ct = 0; ct < 5; ++ct) {
        int c = CW3 + ct * 16 + l15;
        b3ptr[ct] = W2p + (size_t)c * H1D + quad * 8;
    }
    short8 bc3[5];
#pragma unroll
    for (int ct = 0; ct < 5; ++ct) bc3[ct] = *(const short8*)(b3ptr[ct]);

    for (int kc = 0; kc < 6; ++kc) {
        const int k0n = (kc + 1 < 6) ? (kc + 1) * 32 : kc * 32;
        short8 af[2];
#pragma unroll
        for (int rt = 0; rt < 2; ++rt) {
            int r = RW3 + rt * 16 + l15;
            int q = kc * 4 + quad;
            int qs = (q & ~7) | ((q ^ r) & 7);
            af[rt] = *(const short8*)(lds_act1 + r * 384 + qs * 16);
        }
        short8 bn3[5];
#pragma unroll
        for (int ct = 0; ct < 5; ++ct)
            bn3[ct] = *(const short8*)(b3ptr[ct] + k0n);
#pragma unroll
        for (int rt = 0; rt < 2; ++rt)
#pragma unroll
            for (int ct = 0; ct < 5; ++ct)
                acc3[rt][ct] = __builtin_amdgcn_mfma_f32_16x16x32_bf16(af[rt], bc3[ct], acc3[rt][ct], 0, 0, 0);
#pragma unroll
        for (int ct = 0; ct < 5; ++ct) bc3[ct] = bn3[ct];
    }
    { // epilogue 3 -> H2 into lds_act0 (plain [128][160] bf16)
        float bias[5];
#pragma unroll
        for (int ct = 0; ct < 5; ++ct) bias[ct] = b2[bsm * H2D + CW3 + ct * 16 + l15];
#pragma unroll
        for (int rt = 0; rt < 2; ++rt)
#pragma unroll
            for (int ct = 0; ct < 5; ++ct) {
                int col = CW3 + ct * 16 + l15;
#pragma unroll
                for (int rg = 0; rg < 4; ++rg) {
                    int row = RW3 + rt * 16 + quad * 4 + rg;
                    float v = celu_f(acc3[rt][ct][rg] + bias[ct]);
                    *(u16t*)(lds_act0 + (row * H2D + col) * 2) = f2bf(v);
                }
            }
    }
    __syncthreads();

    // ======== Phase 4: e = H2 @ W3 + b3 ; masked sum ; /8 ensemble mean ====
    if (tid < 128) {
        const int row = tid;
        const float* w3 = W3 + bsm * H2D;      // fp32 weights, L1-hot broadcast
        float e = b3[bsm];
#pragma unroll
        for (int k = 0; k < H2D; k += 8) {
            short8 h = *(const short8*)(lds_act0 + (row * H2D + k) * 2);
            float4 wa = *(const float4*)(w3 + k);
            float4 wb = *(const float4*)(w3 + k + 4);
            e += bf2f((u16t)h[0]) * wa.x + bf2f((u16t)h[1]) * wa.y +
                 bf2f((u16t)h[2]) * wa.z + bf2f((u16t)h[3]) * wa.w +
                 bf2f((u16t)h[4]) * wb.x + bf2f((u16t)h[5]) * wb.y +
                 bf2f((u16t)h[6]) * wb.z + bf2f((u16t)h[7]) * wb.w;
        }
        int grow = tile * 128 + row;
        float v = (grow < GRP) ? e * 0.125f : 0.f;
#pragma unroll
        for (int off = 32; off; off >>= 1) v += __shfl_down(v, off);
        if ((tid & 63) == 0) atomicAdd(out, v);
    }
}

// ---------------- host launch ----------------
extern "C" void kernel_launch(void* const* d_in, const int* in_sizes, int n_in,
                              void* d_out, int out_size, void* d_ws, size_t ws_size,
                              hipStream_t stream) {
    const int*   species = (const int*)d_in[0];
    const float* aev     = (const float*)d_in[1];
    const float* W0      = (const float*)d_in[2];
    const float* b0      = (const float*)d_in[3];
    const float* W1      = (const float*)d_in[4];
    const float* b1      = (const float*)d_in[5];
    const float* W2      = (const float*)d_in[6];
    const float* b2      = (const float*)d_in[7];
    const float* W3      = (const float*)d_in[8];
    const float* b3      = (const float*)d_in[9];
    float* out = (float*)d_out;
    char*  ws  = (char*)d_ws;

    int*  cnt    = (int*)(ws + OFF_CNT);
    int*  src_of = (int*)(ws + OFF_SRC);
    u16t* X      = (u16t*)(ws + OFF_X);
    u16t* W0T    = (u16t*)(ws + OFF_W0T);
    u16t* W1T    = (u16t*)(ws + OFF_W1T);
    u16t* W2T    = (u16t*)(ws + OFF_W2T);

    hipMemsetAsync(cnt, 0, 32, stream);
    hipMemsetAsync(d_out, 0, sizeof(float), stream);

    assign_k<<<(NATOMS + 255) / 256, 256, 0, stream>>>(species, cnt, src_of);
    gather_k<<<SSP * GPAD, 256, 0, stream>>>(aev, src_of, X);
    transpose_convert_k<<<dim3(16, 4, 56), 256, 0, stream>>>(W0, W0T, DIN, H0D, KP);
    transpose_convert_k<<<dim3(4, 3, 56), 256, 0, stream>>>(W1, W1T, H0D, H1D, H0D);
    transpose_convert_k<<<dim3(3, 3, 56), 256, 0, stream>>>(W2, W2T, H1D, H2D, H1D);

    fused_mlp<<<dim3(NTILE, 56), 512, 0, stream>>>(X, W0T, W1T, W2T, W3,
                                                   b0, b1, b2, b3, out);
}

// Round 3
// 1070.960 us; speedup vs baseline: 1.1508x; 1.1508x over previous
//
#include <hip/hip_runtime.h>
#include <cstdint>
#include <cstddef>

typedef unsigned short u16t;
typedef __attribute__((ext_vector_type(8))) short short8;   // 8 x bf16 (4 VGPRs)
typedef __attribute__((ext_vector_type(4))) float float4v;  // MFMA C/D frag

#define NATOMS 50400
#define SSP    7
#define DIN    1008
#define KP     1024     // layer-1 K padded
#define GRP    7200     // atoms per species
#define GPAD   7296     // 57 * 128
#define H0D    256
#define H1D    192
#define H2D    160
#define GBSM   28       // bsm per pass (2 passes over 56)

// ---- workspace byte offsets (all 16B aligned) ----
#define OFF_CNT   0ull
#define OFF_SRC   256ull                 // 7*7296*4 = 204288
#define OFF_X     204544ull              // 7*7296*1024*2 = 104595456
#define OFF_W0T   104800000ull           // 56*256*1024*2 = 29360128
#define OFF_W1T   134160128ull           // 56*192*256*2  = 5505024
#define OFF_W2T   139665152ull           // 56*160*192*2  = 3440640
#define OFF_H0    143105792ull           // 28*7296*256*2 = 104595456 -> end 247701248

__device__ __forceinline__ u16t f2bf(float f) {
    union { float f; unsigned u; } x; x.f = f;
    unsigned r = x.u + 0x7fffu + ((x.u >> 16) & 1u);   // RNE
    return (u16t)(r >> 16);
}
__device__ __forceinline__ float bf2f(u16t h) {
    return __uint_as_float(((unsigned)h) << 16);
}
__device__ __forceinline__ float celu_f(float x) {
    return x > 0.f ? x : 0.1f * (__expf(x * 10.f) - 1.f);
}
__device__ __forceinline__ void gll16(const void* g, void* l) {
    __builtin_amdgcn_global_load_lds(
        (const __attribute__((address_space(1))) void*)g,
        (__attribute__((address_space(3))) void*)l, 16, 0, 0);
}

// ---------------- prep kernels ----------------

// atom -> slot within its species block; wave-aggregated atomics
__global__ void assign_k(const int* __restrict__ sp, int* __restrict__ cnt,
                         int* __restrict__ src_of) {
    int i = blockIdx.x * 256 + threadIdx.x;
    int lane = threadIdx.x & 63;
    int s = (i < NATOMS) ? sp[i] : -1;
#pragma unroll
    for (int t = 0; t < SSP; ++t) {
        unsigned long long m = __ballot(s == t);
        if (s == t) {
            int leader = __ffsll((unsigned long long)m) - 1;
            int rank = __popcll(m & ((1ull << lane) - 1ull));
            int base = 0;
            if (lane == leader) base = atomicAdd(&cnt[t], __popcll(m));
            base = __shfl(base, leader);
            src_of[t * GPAD + base + rank] = i;
        }
    }
}

// species-sorted bf16 X [7][7296][1024]; one wave per row, 4 rows/block
__global__ void gather_k(const float* __restrict__ aev, const int* __restrict__ src_of,
                         u16t* __restrict__ X) {
    int wv = threadIdx.x >> 6, lane = threadIdx.x & 63;
    int s = blockIdx.y;
    int r = blockIdx.x * 4 + wv;                 // 0..7295
    int b = s * GPAD + r;
    bool valid = (r < GRP);
    int src = valid ? src_of[b] : 0;
    const float* ap = aev + (size_t)src * DIN;
    u16t* xp = X + (size_t)b * KP;
#pragma unroll
    for (int j = 0; j < 4; ++j) {
        int idx = j * 64 + lane;                 // 0..255
        int c = idx * 4;
        ushort4 o; o.x = 0; o.y = 0; o.z = 0; o.w = 0;
        if (valid && c < DIN) {
            float4 v = *(const float4*)(ap + c);
            o.x = f2bf(v.x); o.y = f2bf(v.y); o.z = f2bf(v.z); o.w = f2bf(v.w);
        }
        *(ushort4*)(xp + c) = o;
    }
}

// src [batch][K_in][C] fp32 -> dst [batch][C][K_out] bf16, zero-fill K_in..K_out
__global__ void transpose_convert_k(const float* __restrict__ src, u16t* __restrict__ dst,
                                    int K_in, int C, int K_out) {
    __shared__ float tile[64][65];
    int b = blockIdx.z;
    int k0 = blockIdx.x * 64, c0 = blockIdx.y * 64;
    int tx = threadIdx.x & 63, ty = threadIdx.x >> 6;
    const float* sp = src + (size_t)b * K_in * C;
#pragma unroll
    for (int i = 0; i < 16; ++i) {
        int kl = i * 4 + ty;
        int k = k0 + kl, c = c0 + tx;
        float v = (k < K_in && c < C) ? sp[(size_t)k * C + c] : 0.f;
        tile[kl][tx] = v;
    }
    __syncthreads();
    u16t* dp = dst + (size_t)b * C * K_out;
#pragma unroll
    for (int i = 0; i < 16; ++i) {
        int cl = i * 4 + ty;
        int c = c0 + cl, k = k0 + tx;
        if (c < C && k < K_out)
            dp[(size_t)c * K_out + k] = f2bf(tile[tx][cl]);
    }
}

// ---------------- layer 1: m97-style GEMM ----------------
// grid (114 = 57 mtiles x 2 ntiles, GBSM), 256 threads (4 waves, 2x2)
__launch_bounds__(256, 3)
__global__ void gemm1(const u16t* __restrict__ X, const u16t* __restrict__ W0T,
                      const float* __restrict__ b0, u16t* __restrict__ H0, int bsm0) {
    __shared__ __attribute__((aligned(16))) char lA[16384];   // [128][64] bf16
    __shared__ __attribute__((aligned(16))) char lB[16384];   // [128][64] bf16

    const int tid = threadIdx.x, w = tid >> 6, lane = tid & 63;
    const int l15 = lane & 15, quad = lane >> 4;
    const int mtile = blockIdx.x >> 1, ntile = blockIdx.x & 1;
    const int by = blockIdx.y, bsm = bsm0 + by, s = bsm >> 3;
    const int wr = w & 1, wc = w >> 1;

    const u16t* Xp = X + ((size_t)s * GPAD + (size_t)mtile * 128) * KP;
    const u16t* Wp = W0T + ((size_t)bsm * H0D + (size_t)ntile * 128) * KP;

    // staging: LDS chunk u holds global chunk (r = u>>3, c = (u&7) ^ (r&7))
    const u16t* gA[4]; const u16t* gB[4];
#pragma unroll
    for (int j = 0; j < 4; ++j) {
        int u = j * 256 + w * 64 + lane;
        int r = u >> 3;
        int cs = (u & 7) ^ (r & 7);
        gA[j] = Xp + (size_t)r * KP + cs * 8;
        gB[j] = Wp + (size_t)r * KP + cs * 8;
    }
    // fragment LDS offsets (constant across K-iters)
    int aoff[4][2], boff[4][2];
#pragma unroll
    for (int rt = 0; rt < 4; ++rt) {
        int r = wr * 64 + rt * 16 + l15;
        int c = wc * 64 + rt * 16 + l15;
#pragma unroll
        for (int ks = 0; ks < 2; ++ks) {
            aoff[rt][ks] = r * 128 + (((ks * 4 + quad) ^ (r & 7)) * 16);
            boff[rt][ks] = c * 128 + (((ks * 4 + quad) ^ (c & 7)) * 16);
        }
    }

    float4v acc[4][4];
#pragma unroll
    for (int i = 0; i < 4; ++i)
#pragma unroll
        for (int j = 0; j < 4; ++j) acc[i][j] = (float4v){0.f, 0.f, 0.f, 0.f};

    for (int kt = 0; kt < 16; ++kt) {
        const int ko = kt * 64;
        __syncthreads();                         // prev reads done
#pragma unroll
        for (int j = 0; j < 4; ++j) {
            gll16(gA[j] + ko, lA + j * 4096 + w * 1024);
            gll16(gB[j] + ko, lB + j * 4096 + w * 1024);
        }
        __syncthreads();                         // staging done (vmcnt drain)
#pragma unroll
        for (int ks = 0; ks < 2; ++ks) {
            short8 a[4], b[4];
#pragma unroll
            for (int rt = 0; rt < 4; ++rt) a[rt] = *(const short8*)(lA + aoff[rt][ks]);
#pragma unroll
            for (int ct = 0; ct < 4; ++ct) b[ct] = *(const short8*)(lB + boff[ct][ks]);
#pragma unroll
            for (int rt = 0; rt < 4; ++rt)
#pragma unroll
                for (int ct = 0; ct < 4; ++ct)
                    acc[rt][ct] = __builtin_amdgcn_mfma_f32_16x16x32_bf16(a[rt], b[ct], acc[rt][ct], 0, 0, 0);
        }
    }

    // epilogue: bias + celu -> H0[by][row][col] bf16
    float bias[4];
#pragma unroll
    for (int ct = 0; ct < 4; ++ct)
        bias[ct] = b0[bsm * H0D + ntile * 128 + wc * 64 + ct * 16 + l15];
    u16t* Hp = H0 + (size_t)by * GPAD * H0D;
#pragma unroll
    for (int rt = 0; rt < 4; ++rt)
#pragma unroll
        for (int ct = 0; ct < 4; ++ct) {
            int col = ntile * 128 + wc * 64 + ct * 16 + l15;
#pragma unroll
            for (int rg = 0; rg < 4; ++rg) {
                int row = mtile * 128 + wr * 64 + rt * 16 + quad * 4 + rg;
                Hp[(size_t)row * H0D + col] = f2bf(celu_f(acc[rt][ct][rg] + bias[ct]));
            }
        }
}

// ---------------- layers 2-4 per 64-row tile ----------------
// grid (114, GBSM), 256 threads (4 waves: wr2 = w&1 rows, wc2 = w>>1 cols)
__launch_bounds__(256, 2)
__global__ void mlp234(const u16t* __restrict__ H0, const u16t* __restrict__ W1T,
                       const u16t* __restrict__ W2T, const float* __restrict__ W3,
                       const float* __restrict__ b1, const float* __restrict__ b2,
                       const float* __restrict__ b3, float* __restrict__ out, int bsm0) {
    __shared__ __attribute__((aligned(16))) char lH0[32768];  // [64][256] bf16 swizzled
    __shared__ __attribute__((aligned(16))) char lH1[24576];  // [64][192] bf16 swizzled
    __shared__ __attribute__((aligned(16))) char lH2[20480];  // [64][160] bf16 plain
    __shared__ float red[4];

    const int tid = threadIdx.x, w = tid >> 6, lane = tid & 63;
    const int l15 = lane & 15, quad = lane >> 4;
    const int by = blockIdx.y, bsm = bsm0 + by;
    const int g0 = blockIdx.x * 64;
    const int wr2 = w & 1, wc2 = w >> 1;

    // ---- stage H0 tile [64][256] via gll16; chunk u: r=u>>5, c'=u&31,
    //      src chunk c = (c'&24) | ((c'^r)&7)
    const u16t* Hg = H0 + ((size_t)by * GPAD + g0) * H0D;
#pragma unroll
    for (int j = 0; j < 8; ++j) {
        int u = j * 256 + w * 64 + lane;
        int r = u >> 5, c5 = u & 31;
        int cs = (c5 & 24) | ((c5 ^ r) & 7);
        gll16(Hg + (size_t)r * H0D + cs * 8, lH0 + j * 4096 + w * 1024);
    }

    // weight pointers (fragment-shaped, L2-hot)
    const u16t* W1p = W1T + (size_t)bsm * H1D * H0D;   // [192][256]
    const u16t* W2p = W2T + (size_t)bsm * H2D * H1D;   // [160][192]
    const u16t* bp1[6];
#pragma unroll
    for (int ct = 0; ct < 6; ++ct)
        bp1[ct] = W1p + (size_t)(wc2 * 96 + ct * 16 + l15) * H0D + quad * 8;

    __syncthreads();                                   // H0 staged

    // ---- layer 2: C2[64 x 192] = H0 @ W1 ----
    float4v acc2[2][6];
#pragma unroll
    for (int i = 0; i < 2; ++i)
#pragma unroll
        for (int j = 0; j < 6; ++j) acc2[i][j] = (float4v){0.f, 0.f, 0.f, 0.f};
    short8 bc[6];
#pragma unroll
    for (int ct = 0; ct < 6; ++ct) bc[ct] = *(const short8*)(bp1[ct]);

    for (int kc = 0; kc < 8; ++kc) {
        const int kn = ((kc + 1 < 8) ? kc + 1 : kc) * 32;
        short8 a[2];
#pragma unroll
        for (int rt = 0; rt < 2; ++rt) {
            int r = wr2 * 32 + rt * 16 + l15;
            int ch = kc * 4 + quad;
            int sw = (ch & 24) | ((ch ^ r) & 7);
            a[rt] = *(const short8*)(lH0 + r * 512 + sw * 16);
        }
        short8 bn[6];
#pragma unroll
        for (int ct = 0; ct < 6; ++ct) bn[ct] = *(const short8*)(bp1[ct] + kn);
#pragma unroll
        for (int rt = 0; rt < 2; ++rt)
#pragma unroll
            for (int ct = 0; ct < 6; ++ct)
                acc2[rt][ct] = __builtin_amdgcn_mfma_f32_16x16x32_bf16(a[rt], bc[ct], acc2[rt][ct], 0, 0, 0);
#pragma unroll
        for (int ct = 0; ct < 6; ++ct) bc[ct] = bn[ct];
    }
    { // epilogue 2 -> lH1 [64][192], chunk swizzle low3
        float bias[6];
#pragma unroll
        for (int ct = 0; ct < 6; ++ct) bias[ct] = b1[bsm * H1D + wc2 * 96 + ct * 16 + l15];
#pragma unroll
        for (int rt = 0; rt < 2; ++rt)
#pragma unroll
            for (int ct = 0; ct < 6; ++ct) {
                int h = wc2 * 96 + ct * 16 + l15;
                int ch = h >> 3;
#pragma unroll
                for (int rg = 0; rg < 4; ++rg) {
                    int g = wr2 * 32 + rt * 16 + quad * 4 + rg;
                    float v = celu_f(acc2[rt][ct][rg] + bias[ct]);
                    int sw = (ch & ~7) | ((ch ^ g) & 7);
                    *(u16t*)(lH1 + g * 384 + sw * 16 + (h & 7) * 2) = f2bf(v);
                }
            }
    }
    __syncthreads();

    // ---- layer 3: C3[64 x 160] = H1 @ W2 ----
    float4v acc3[2][5];
#pragma unroll
    for (int i = 0; i < 2; ++i)
#pragma unroll
        for (int j = 0; j < 5; ++j) acc3[i][j] = (float4v){0.f, 0.f, 0.f, 0.f};
    const u16t* bp2[5];
#pragma unroll
    for (int ct = 0; ct < 5; ++ct)
        bp2[ct] = W2p + (size_t)(wc2 * 80 + ct * 16 + l15) * H1D + quad * 8;
    short8 bc3[5];
#pragma unroll
    for (int ct = 0; ct < 5; ++ct) bc3[ct] = *(const short8*)(bp2[ct]);

    for (int kc = 0; kc < 6; ++kc) {
        const int kn = ((kc + 1 < 6) ? kc + 1 : kc) * 32;
        short8 a[2];
#pragma unroll
        for (int rt = 0; rt < 2; ++rt) {
            int r = wr2 * 32 + rt * 16 + l15;
            int ch = kc * 4 + quad;
            int sw = (ch & ~7) | ((ch ^ r) & 7);
            a[rt] = *(const short8*)(lH1 + r * 384 + sw * 16);
        }
        short8 bn[5];
#pragma unroll
        for (int ct = 0; ct < 5; ++ct) bn[ct] = *(const short8*)(bp2[ct] + kn);
#pragma unroll
        for (int rt = 0; rt < 2; ++rt)
#pragma unroll
            for (int ct = 0; ct < 5; ++ct)
                acc3[rt][ct] = __builtin_amdgcn_mfma_f32_16x16x32_bf16(a[rt], bc3[ct], acc3[rt][ct], 0, 0, 0);
#pragma unroll
        for (int ct = 0; ct < 5; ++ct) bc3[ct] = bn[ct];
    }
    { // epilogue 3 -> lH2 [64][160] plain
        float bias[5];
#pragma unroll
        for (int ct = 0; ct < 5; ++ct) bias[ct] = b2[bsm * H2D + wc2 * 80 + ct * 16 + l15];
#pragma unroll
        for (int rt = 0; rt < 2; ++rt)
#pragma unroll
            for (int ct = 0; ct < 5; ++ct) {
                int col = wc2 * 80 + ct * 16 + l15;
#pragma unroll
                for (int rg = 0; rg < 4; ++rg) {
                    int g = wr2 * 32 + rt * 16 + quad * 4 + rg;
                    float v = celu_f(acc3[rt][ct][rg] + bias[ct]);
                    *(u16t*)(lH2 + (g * H2D + col) * 2) = f2bf(v);
                }
            }
    }
    __syncthreads();

    // ---- layer 4: e = H2 @ W3 + b3 ; mask ; mean/8 ; block reduce ----
    {
        int row = tid >> 2, part = tid & 3;
        const char* h2 = lH2 + row * 320 + part * 80;
        const float* w3 = W3 + bsm * H2D + part * 40;
        float e = 0.f;
#pragma unroll
        for (int k = 0; k < 40; k += 8) {
            short8 h = *(const short8*)(h2 + k * 2);
            e += bf2f((u16t)h[0]) * w3[k]     + bf2f((u16t)h[1]) * w3[k + 1] +
                 bf2f((u16t)h[2]) * w3[k + 2] + bf2f((u16t)h[3]) * w3[k + 3] +
                 bf2f((u16t)h[4]) * w3[k + 4] + bf2f((u16t)h[5]) * w3[k + 5] +
                 bf2f((u16t)h[6]) * w3[k + 6] + bf2f((u16t)h[7]) * w3[k + 7];
        }
        if (part == 0) e += b3[bsm];
        e += __shfl_down(e, 2);
        e += __shfl_down(e, 1);
        int g = g0 + row;
        float v = (part == 0 && g < GRP) ? e : 0.f;
#pragma unroll
        for (int off = 32; off; off >>= 1) v += __shfl_down(v, off);
        if (lane == 0) red[w] = v;
    }
    __syncthreads();
    if (tid == 0) atomicAdd(out, (red[0] + red[1] + red[2] + red[3]) * 0.125f);
}

// ---------------- host launch ----------------
extern "C" void kernel_launch(void* const* d_in, const int* in_sizes, int n_in,
                              void* d_out, int out_size, void* d_ws, size_t ws_size,
                              hipStream_t stream) {
    const int*   species = (const int*)d_in[0];
    const float* aev     = (const float*)d_in[1];
    const float* W0      = (const float*)d_in[2];
    const float* b0      = (const float*)d_in[3];
    const float* W1      = (const float*)d_in[4];
    const float* b1      = (const float*)d_in[5];
    const float* W2      = (const float*)d_in[6];
    const float* b2      = (const float*)d_in[7];
    const float* W3      = (const float*)d_in[8];
    const float* b3      = (const float*)d_in[9];
    float* out = (float*)d_out;
    char*  ws  = (char*)d_ws;

    int*  cnt    = (int*)(ws + OFF_CNT);
    int*  src_of = (int*)(ws + OFF_SRC);
    u16t* X      = (u16t*)(ws + OFF_X);
    u16t* W0T    = (u16t*)(ws + OFF_W0T);
    u16t* W1T    = (u16t*)(ws + OFF_W1T);
    u16t* W2T    = (u16t*)(ws + OFF_W2T);
    u16t* H0     = (u16t*)(ws + OFF_H0);

    hipMemsetAsync(cnt, 0, 32, stream);
    hipMemsetAsync(d_out, 0, sizeof(float), stream);

    assign_k<<<(NATOMS + 255) / 256, 256, 0, stream>>>(species, cnt, src_of);
    gather_k<<<dim3(GPAD / 4, SSP), 256, 0, stream>>>(aev, src_of, X);
    transpose_convert_k<<<dim3(16, 4, 56), 256, 0, stream>>>(W0, W0T, DIN, H0D, KP);
    transpose_convert_k<<<dim3(4, 3, 56), 256, 0, stream>>>(W1, W1T, H0D, H1D, H0D);
    transpose_convert_k<<<dim3(3, 3, 56), 256, 0, stream>>>(W2, W2T, H1D, H2D, H1D);

    for (int p = 0; p < 2; ++p) {
        gemm1<<<dim3(114, GBSM), 256, 0, stream>>>(X, W0T, b0, H0, p * GBSM);
        mlp234<<<dim3(114, GBSM), 256, 0, stream>>>(H0, W1T, W2T, W3,
                                                    b1, b2, b3, out, p * GBSM);
    }
}